// Round 1
// baseline (345.676 us; speedup 1.0000x reference)
//
#include <hip/hip_runtime.h>

// Interpolate1D: stride-2 linear upsample along axis 1.
//   x:   (B=16, N=8192, C=256) fp32
//   out: (B=16, 2N=16384, C=256) fp32
//   out[:,2k,:]   = x[:,k,:]
//   out[:,2k+1,:] = 0.5*(x[:,k,:] + x[:,k+1,:])   (k<N-1)
//   out[:,2N-1,:] = x[:,N-1,:]
//
// Memory-bound: 128 MiB read + 256 MiB write. One thread per input float4;
// a 64-lane wave covers exactly one 1 KiB C-row, so all loads/stores are
// fully coalesced 1 KiB wave transactions.

#define C4   64      // 256 floats / 4
#define NROW 8192
#define BATCH 16

__global__ __launch_bounds__(256) void Interpolate1D_kernel(
    const float4* __restrict__ x, float4* __restrict__ out) {
    // total input float4s = 16 * 8192 * 64 = 8,388,608
    unsigned int i = blockIdx.x * blockDim.x + threadIdx.x;

    unsigned int c4 = i & (C4 - 1);          // 0..63
    unsigned int k  = (i >> 6) & (NROW - 1); // 0..8191
    unsigned int b  = i >> 19;               // 0..15

    float4 a = x[i];
    float4 nb = (k < NROW - 1) ? x[i + C4] : a;

    float4 mid;
    mid.x = 0.5f * (a.x + nb.x);
    mid.y = 0.5f * (a.y + nb.y);
    mid.z = 0.5f * (a.z + nb.z);
    mid.w = 0.5f * (a.w + nb.w);

    // output row index 2k (even) and 2k+1 (odd), row stride C4 float4s
    size_t o = (((size_t)b * (2 * NROW) + 2 * k) << 6) + c4;
    out[o] = a;
    out[o + C4] = mid;
}

extern "C" void kernel_launch(void* const* d_in, const int* in_sizes, int n_in,
                              void* d_out, int out_size, void* d_ws, size_t ws_size,
                              hipStream_t stream) {
    const float4* x = (const float4*)d_in[0];
    float4* out = (float4*)d_out;

    const unsigned int total4 = BATCH * NROW * C4;  // 8,388,608
    const unsigned int block = 256;
    const unsigned int grid = total4 / block;       // 32,768
    Interpolate1D_kernel<<<grid, block, 0, stream>>>(x, out);
}

// Round 3
// 345.420 us; speedup vs baseline: 1.0007x; 1.0007x over previous
//
#include <hip/hip_runtime.h>

// Interpolate1D: stride-2 linear upsample along axis 1.
//   x:   (B=16, N=8192, C=256) fp32  (128 MiB)
//   out: (B=16, 2N=16384, C=256) fp32 (256 MiB)
//   out[:,2k,:]   = x[:,k,:]
//   out[:,2k+1,:] = 0.5*(x[:,k,:] + x[:,k+1,:])   (k<N-1)
//   out[:,2N-1,:] = x[:,N-1,:]
//
// Pure HBM-bound (402 MB min traffic -> ~64 us floor at 6.3 TB/s).
// One thread per input float4; a 64-lane wave covers exactly one 1 KiB
// C-row, so loads and both stores are fully coalesced 1 KiB wave
// transactions. Stores are nontemporal (native ext_vector_type for the
// builtin): out is written once and never read, so keep it out of L2 to
// protect the x[k+1] re-read locality.

#define C4   64      // 256 floats / 4
#define NROW 8192
#define BATCH 16

typedef float vfloat4 __attribute__((ext_vector_type(4)));

__global__ __launch_bounds__(256) void Interpolate1D_kernel(
    const vfloat4* __restrict__ x, vfloat4* __restrict__ out) {
    unsigned int i = blockIdx.x * blockDim.x + threadIdx.x;

    unsigned int c4 = i & (C4 - 1);          // 0..63
    unsigned int k  = (i >> 6) & (NROW - 1); // 0..8191

    vfloat4 a = x[i];
    vfloat4 nb = (k < NROW - 1) ? x[i + C4] : a;

    vfloat4 mid = 0.5f * (a + nb);

    // even out row 2k at float4 index 2*i - c4; odd row is +C4 (next 1 KiB row)
    size_t o = ((size_t)i << 1) - c4;
    __builtin_nontemporal_store(a,   &out[o]);
    __builtin_nontemporal_store(mid, &out[o + C4]);
}

extern "C" void kernel_launch(void* const* d_in, const int* in_sizes, int n_in,
                              void* d_out, int out_size, void* d_ws, size_t ws_size,
                              hipStream_t stream) {
    const vfloat4* x = (const vfloat4*)d_in[0];
    vfloat4* out = (vfloat4*)d_out;

    const unsigned int total4 = BATCH * NROW * C4;  // 8,388,608
    const unsigned int block = 256;
    const unsigned int grid = total4 / block;       // 32,768
    Interpolate1D_kernel<<<grid, block, 0, stream>>>(x, out);
}